// Round 6
// baseline (43.999 us; speedup 1.0000x reference)
//
#include <hip/hip_runtime.h>
#include <hip/hip_cooperative_groups.h>
#include <math.h>

namespace cg = cooperative_groups;

// Problem dims (fixed by reference setup_inputs)
#define BB 32
#define LL 8192
#define DD 256
#define QQ 512
#define HH 256
#define MM 5
#define PRUNE_LEFT  (-50)
#define PRUNE_RIGHT (50)

__device__ inline float wave_reduce_add(float v) {
    #pragma unroll
    for (int m = 1; m < 64; m <<= 1)
        v += __shfl_xor(v, m, 64);
    return v;
}

// Single cooperative kernel. Grid = 256 blocks x 256 threads.
// Block g: batch b = g>>3, chunk c = g&7.
// Phase A: proj rows [c*32,c*32+32) (coalesced W1) + partial stats sums -> ws
//          (agent-scope atomics for cross-XCD visibility); c==0 blocks also
//          issue a speculative warm prefetch of ctx rows [0,64).
// grid.sync()
// Phase B: finish stats (redundant, 15 threads/block), write dense p_ctx
//          slice (exact reference math incl. prune mask); c==0 blocks compute
//          expected[b,:] over the exact nonzero window.
__global__ void __launch_bounds__(256, 1) k_all(
    const float* __restrict__ ctx,
    const float* __restrict__ query,
    const float* __restrict__ W1,
    const float* __restrict__ b1,
    const float* __restrict__ W2,
    const float* __restrict__ b2,
    float* __restrict__ expected,
    float* __restrict__ p_ctx,
    float* __restrict__ ws)
{
    __shared__ float s_proj[32];
    __shared__ float s_stats[3 * MM];
    __shared__ float s_pw[256];

    const int g    = blockIdx.x;
    const int b    = g >> 3;
    const int c    = g & 7;
    const int t    = threadIdx.x;
    const int lane = t & 63;
    const int w    = t >> 6;   // wave 0..3

    const float* cb = ctx + (size_t)b * LL * DD;

    // ---- speculative warm prefetch (c==0): ctx rows [0,64), 16 float4/thread ----
    float4 pf[16];
    if (c == 0) {
        const float4* cp = (const float4*)cb;   // 64 rows = 4096 float4
        #pragma unroll
        for (int i = 0; i < 16; ++i) pf[i] = cp[i * 256 + t];
    }

    // ---- Phase A: proj rows [c*32, c*32+32), 8 rows per wave ----
    const float4* q4 = (const float4*)(query + (size_t)b * QQ);  // 128 float4
    const float4 qa = q4[lane];
    const float4 qb = q4[64 + lane];
    const float4* W1_4 = (const float4*)W1;   // row h = 128 float4

    #pragma unroll
    for (int r = 0; r < 8; ++r) {
        const int h = c * 32 + w * 8 + r;
        const float4 wa = W1_4[(size_t)h * 128 + lane];
        const float4 wb = W1_4[(size_t)h * 128 + 64 + lane];
        float acc = wa.x * qa.x + wa.y * qa.y + wa.z * qa.z + wa.w * qa.w
                  + wb.x * qb.x + wb.y * qb.y + wb.z * qb.z + wb.w * qb.w;
        acc = wave_reduce_add(acc);
        if (lane == 0) s_proj[w * 8 + r] = tanhf(acc + b1[h]);
    }
    __syncthreads();

    // ---- partial stats: ws[(b*8+c)*16 + j] = sum over this chunk's 32 h ----
    if (t < 3 * MM) {
        float s = 0.f;
        const float* w2r = W2 + (size_t)t * HH + c * 32;
        #pragma unroll
        for (int r = 0; r < 32; ++r) s += s_proj[r] * w2r[r];
        __hip_atomic_store(&ws[(size_t)(b * 8 + c) * 16 + t], s,
                           __ATOMIC_RELAXED, __HIP_MEMORY_SCOPE_AGENT);
    }

    // keep prefetch registers alive without using results
    if (c == 0) {
        float keep = 0.f;
        #pragma unroll
        for (int i = 0; i < 16; ++i) keep += pf[i].x + pf[i].y + pf[i].z + pf[i].w;
        asm volatile("" :: "v"(keep));
    }

    cg::this_grid().sync();

    // ---- Phase B: finish stats (redundant per block) ----
    if (t < 3 * MM) {
        float s = 0.f;
        #pragma unroll
        for (int cc = 0; cc < 8; ++cc)
            s += __hip_atomic_load(&ws[(size_t)(b * 8 + cc) * 16 + t],
                                   __ATOMIC_RELAXED, __HIP_MEMORY_SCOPE_AGENT);
        s_stats[t] = expf(s + b2[t]);
    }
    __syncthreads();

    float alpha[MM], beta[MM], kappa[MM], cen[MM];
    #pragma unroll
    for (int m = 0; m < MM; ++m) {
        alpha[m] = s_stats[m];
        beta[m]  = s_stats[MM + m];
        kappa[m] = s_stats[2 * MM + m];
        cen[m]   = rintf(kappa[m]);   // round-half-even = jnp.round
    }

    // ---- dense p_ctx slice [c*1024, (c+1)*1024), exact reference math ----
    float* pb = p_ctx + (size_t)b * LL + c * 1024;
    #pragma unroll
    for (int k = 0; k < 4; ++k) {
        const int l = c * 1024 + k * 256 + t;
        const float pos = (float)l;
        float p = 0.f;
        #pragma unroll
        for (int m = 0; m < MM; ++m) {
            if (pos >= cen[m] + (float)PRUNE_LEFT && pos < cen[m] + (float)(PRUNE_RIGHT + 1)) {
                const float diff = pos - kappa[m];
                p += alpha[m] * expf(-beta[m] * diff * diff);
            }
        }
        pb[k * 256 + t] = p;
    }

    if (c != 0) return;

    // ---- expected[b, :] over the exact nonzero window (c==0 blocks) ----
    float cmin = 1e30f, cmax = -1e30f;
    #pragma unroll
    for (int m = 0; m < MM; ++m) {
        cmin = fminf(cmin, cen[m]);
        cmax = fmaxf(cmax, cen[m]);
    }
    const float lof = fminf(fmaxf(0.f, cmin + (float)PRUNE_LEFT), (float)LL);
    const float hif = fminf(fmaxf(0.f, cmax + (float)(PRUNE_RIGHT + 1)), (float)LL);
    const int lo = (int)lof;
    const int hi = ((int)hif < lo) ? lo : (int)hif;

    float acc = 0.f;
    for (int base = lo; base < hi; base += 256) {
        const int n = min(256, hi - base);
        __syncthreads();
        if (t < n) {
            const float pos = (float)(base + t);
            float p = 0.f;
            #pragma unroll
            for (int m = 0; m < MM; ++m) {
                if (pos >= cen[m] + (float)PRUNE_LEFT && pos < cen[m] + (float)(PRUNE_RIGHT + 1)) {
                    const float diff = pos - kappa[m];
                    p += alpha[m] * expf(-beta[m] * diff * diff);
                }
            }
            s_pw[t] = p;
        }
        __syncthreads();
        #pragma unroll 8
        for (int i = 0; i < n; ++i) {
            acc += s_pw[i] * cb[(size_t)(base + i) * DD + t];   // coalesced, L1/L2-warm
        }
    }
    expected[(size_t)b * DD + t] = acc;
}

extern "C" void kernel_launch(void* const* d_in, const int* in_sizes, int n_in,
                              void* d_out, int out_size, void* d_ws, size_t ws_size,
                              hipStream_t stream) {
    const float* ctx   = (const float*)d_in[0];
    const float* query = (const float*)d_in[1];
    const float* W1    = (const float*)d_in[2];
    const float* b1    = (const float*)d_in[3];
    const float* W2    = (const float*)d_in[4];
    const float* b2    = (const float*)d_in[5];

    float* out      = (float*)d_out;
    float* expected = out;             // (B, D)  = 8192 floats
    float* p_ctx    = out + BB * DD;   // (B, L)  = 262144 floats
    float* ws       = (float*)d_ws;    // (B, 8, 16) partial stats sums

    void* args[] = {&ctx, &query, &W1, &b1, &W2, &b2, &expected, &p_ctx, &ws};
    hipLaunchCooperativeKernel((void*)k_all, dim3(BB * 8), dim3(256), args, 0, stream);
}

// Round 7
// 15.033 us; speedup vs baseline: 2.9268x; 2.9268x over previous
//
#include <hip/hip_runtime.h>
#include <math.h>

// Problem dims (fixed by reference setup_inputs)
#define BB 32
#define LL 8192
#define DD 256
#define QQ 512
#define HH 256
#define MM 5
#define PRUNE_LEFT  (-50)
#define PRUNE_RIGHT (50)

__device__ inline float wave_reduce_add(float v) {
    #pragma unroll
    for (int m = 1; m < 64; m <<= 1)
        v += __shfl_xor(v, m, 64);
    return v;
}

// Kernel 1: grid (8, 32) x 256. Block (c,b): proj rows [c*32, c*32+32)
// (coalesced float4 W1, 8 rows/wave), then the 15 partial W2.proj sums over
// this 32-column slice -> ws[(b*8+c)*16 + j] (plain store, overwritten each
// replay; visible to kernel 2 via stream kernel-boundary ordering).
__global__ void __launch_bounds__(256) k_proj(const float* __restrict__ query,
                                              const float* __restrict__ W1,
                                              const float* __restrict__ b1,
                                              const float* __restrict__ W2,
                                              float* __restrict__ ws) {
    __shared__ float s_proj[32];
    const int b    = blockIdx.y;
    const int c    = blockIdx.x;    // 0..7
    const int t    = threadIdx.x;
    const int lane = t & 63;
    const int w    = t >> 6;        // 0..3

    const float4* q4 = (const float4*)(query + (size_t)b * QQ);  // 128 float4
    const float4 qa = q4[lane];
    const float4 qb = q4[64 + lane];
    const float4* W1_4 = (const float4*)W1;   // row h = 128 float4

    #pragma unroll
    for (int r = 0; r < 8; ++r) {
        const int h = c * 32 + w * 8 + r;
        const float4 wa = W1_4[(size_t)h * 128 + lane];
        const float4 wb = W1_4[(size_t)h * 128 + 64 + lane];
        float acc = wa.x * qa.x + wa.y * qa.y + wa.z * qa.z + wa.w * qa.w
                  + wb.x * qb.x + wb.y * qb.y + wb.z * qb.z + wb.w * qb.w;
        acc = wave_reduce_add(acc);
        if (lane == 0) s_proj[w * 8 + r] = tanhf(acc + b1[h]);
    }
    __syncthreads();

    if (t < 3 * MM) {
        const float4* w2r = (const float4*)(W2 + (size_t)t * HH + c * 32);  // 8 float4
        float s = 0.f;
        #pragma unroll
        for (int r = 0; r < 8; ++r) {
            const float4 v = w2r[r];
            s += v.x * s_proj[r * 4 + 0] + v.y * s_proj[r * 4 + 1]
               + v.z * s_proj[r * 4 + 2] + v.w * s_proj[r * 4 + 3];
        }
        ws[(size_t)(b * 8 + c) * 16 + t] = s;
    }
}

// Kernel 2: grid (9, 32) x 1024. Every block finishes stats redundantly
// (15 threads x 8 partials + exp). Blocks s<8: dense p_ctx slice (exact
// reference math incl. prune mask), 1 position/thread. Block s==8: expected
// over the exact nonzero window, ctx rows [0,128) prefetched at entry.
__global__ void __launch_bounds__(1024) k_main(const float* __restrict__ ctx,
                                               const float* __restrict__ ws,
                                               const float* __restrict__ b2,
                                               float* __restrict__ p_ctx,
                                               float* __restrict__ expected) {
    __shared__ float s_stats[3 * MM];
    __shared__ float s_pw[1024];
    __shared__ float s_part[4][DD];

    const int b = blockIdx.y;
    const int s = blockIdx.x;
    const int t = threadIdx.x;

    const float* cb = ctx + (size_t)b * LL * DD;

    // ---- speculative warm prefetch (expected block only): rows [0,128) ----
    float4 pf[8];
    if (s == 8) {
        const float4* cp = (const float4*)cb;   // 128 rows = 8192 float4
        #pragma unroll
        for (int i = 0; i < 8; ++i) pf[i] = cp[(size_t)i * 1024 + t];
    }

    // ---- finish stats: sum 8 partials + bias, exp ----
    if (t < 3 * MM) {
        float acc = 0.f;
        #pragma unroll
        for (int cc = 0; cc < 8; ++cc)
            acc += ws[(size_t)(b * 8 + cc) * 16 + t];
        s_stats[t] = expf(acc + b2[t]);
    }
    __syncthreads();

    float alpha[MM], beta[MM], kappa[MM], cen[MM];
    #pragma unroll
    for (int m = 0; m < MM; ++m) {
        alpha[m] = s_stats[m];
        beta[m]  = s_stats[MM + m];
        kappa[m] = s_stats[2 * MM + m];
        cen[m]   = rintf(kappa[m]);   // round-half-even = jnp.round
    }

    if (s < 8) {
        // ---- dense p_ctx slice (exact reference math incl. prune mask) ----
        const int l = s * 1024 + t;
        const float pos = (float)l;
        float p = 0.f;
        #pragma unroll
        for (int m = 0; m < MM; ++m) {
            if (pos >= cen[m] + (float)PRUNE_LEFT && pos < cen[m] + (float)(PRUNE_RIGHT + 1)) {
                const float diff = pos - kappa[m];
                p += alpha[m] * expf(-beta[m] * diff * diff);
            }
        }
        p_ctx[(size_t)b * LL + l] = p;
        return;
    }

    // ---- expected[b, :] over the exact nonzero window ----
    float cmin = 1e30f, cmax = -1e30f;
    #pragma unroll
    for (int m = 0; m < MM; ++m) {
        cmin = fminf(cmin, cen[m]);
        cmax = fmaxf(cmax, cen[m]);
    }
    const float lof = fminf(fmaxf(0.f, cmin + (float)PRUNE_LEFT), (float)LL);
    const float hif = fminf(fmaxf(0.f, cmax + (float)(PRUNE_RIGHT + 1)), (float)LL);
    const int lo = (int)lof;
    const int hi = ((int)hif < lo) ? lo : (int)hif;

    // keep prefetch registers alive without using results
    {
        float keep = 0.f;
        #pragma unroll
        for (int i = 0; i < 8; ++i) keep += pf[i].x + pf[i].y + pf[i].z + pf[i].w;
        asm volatile("" :: "v"(keep));
    }

    const int d  = t & 255;   // output column
    const int wq = t >> 8;    // row-quarter 0..3

    float acc = 0.f;
    for (int base = lo; base < hi; base += 1024) {
        const int n = min(1024, hi - base);
        __syncthreads();
        if (t < n) {
            const float pos = (float)(base + t);
            float p = 0.f;
            #pragma unroll
            for (int m = 0; m < MM; ++m) {
                if (pos >= cen[m] + (float)PRUNE_LEFT && pos < cen[m] + (float)(PRUNE_RIGHT + 1)) {
                    const float diff = pos - kappa[m];
                    p += alpha[m] * expf(-beta[m] * diff * diff);
                }
            }
            s_pw[t] = p;
        }
        __syncthreads();
        #pragma unroll 4
        for (int r = wq; r < n; r += 4) {
            acc += s_pw[r] * cb[(size_t)(base + r) * DD + d];   // coalesced, warm
        }
    }
    s_part[wq][d] = acc;
    __syncthreads();
    if (t < DD) {
        expected[(size_t)b * DD + t] =
            s_part[0][t] + s_part[1][t] + s_part[2][t] + s_part[3][t];
    }
}

extern "C" void kernel_launch(void* const* d_in, const int* in_sizes, int n_in,
                              void* d_out, int out_size, void* d_ws, size_t ws_size,
                              hipStream_t stream) {
    const float* ctx   = (const float*)d_in[0];
    const float* query = (const float*)d_in[1];
    const float* W1    = (const float*)d_in[2];
    const float* b1    = (const float*)d_in[3];
    const float* W2    = (const float*)d_in[4];
    const float* b2    = (const float*)d_in[5];

    float* out      = (float*)d_out;
    float* expected = out;             // (B, D)  = 8192 floats
    float* p_ctx    = out + BB * DD;   // (B, L)  = 262144 floats
    float* ws       = (float*)d_ws;    // (B, 8, 16) partial W2.proj sums

    dim3 g1(8, BB);
    k_proj<<<g1, 256, 0, stream>>>(query, W1, b1, W2, ws);

    dim3 g2(9, BB);
    k_main<<<g2, 1024, 0, stream>>>(ctx, ws, b2, p_ctx, expected);
}